// Round 3
// baseline (110.834 us; speedup 1.0000x reference)
//
#include <hip/hip_runtime.h>

// MorphoMLP: y = relu(maxplus(relu(maxplus(x,W1)), W2)), fp32.
// B=512, IN=512, HID=1024, OUT=512.
// R3: 128x128 tiles, 8x8 frag/thread (VALU-bound inner loop), single K-stage,
//     256 blocks = 1 block/CU per morpho.
//   transpose3 -> morpho3<1024> (z=8) -> combineH -> morpho3<512> (z=16)
//   -> combineY (max16 + relu + transpose)
// ws: xT 1MB | W1T 2MB | W2T 2MB | hp 16MB | A2 2MB | yp 16MB = 39MB

#define WS_XT   0                          // [512][512]    x^T  [k][b]
#define WS_W1T  (512 * 512)                // [512][1024]   W1^T [k][j]
#define WS_W2T  (WS_W1T + 512 * 1024)      // [1024][512]   W2^T [k2][o]
#define WS_HP   (WS_W2T + 1024 * 512)      // [8][1024][512]  L1 partials
#define WS_A2   (WS_HP + 8 * 1024 * 512)   // [1024][512]   relu(h)^T [k2][b]
#define WS_YP   (WS_A2 + 1024 * 512)       // [16][512][512]  L2 partials

// ---------------------------------------------------------------------------
// Fused transpose of x (512x512), W1 (1024x512), W2 (512x1024) into ws.
__global__ __launch_bounds__(256) void transpose3(const float* __restrict__ x,
                                                  const float* __restrict__ W1,
                                                  const float* __restrict__ W2,
                                                  float* __restrict__ ws) {
    __shared__ float t[32][33];
    const int id = blockIdx.x;
    const float* src;
    float* dst;
    int R, C, rt, ct;
    if (id < 256) {
        src = x;  dst = ws + WS_XT;  R = 512;  C = 512;
        rt = id >> 4;          ct = id & 15;
    } else if (id < 768) {
        int b = id - 256;
        src = W1; dst = ws + WS_W1T; R = 1024; C = 512;
        rt = b >> 4;           ct = b & 15;
    } else {
        int b = id - 768;
        src = W2; dst = ws + WS_W2T; R = 512;  C = 1024;
        rt = b >> 5;           ct = b & 31;
    }
    const int tx = threadIdx.x & 31, ty = threadIdx.x >> 5;
    const int r0 = rt * 32, c0 = ct * 32;
#pragma unroll
    for (int r = 0; r < 4; r++)
        t[ty + 8 * r][tx] = src[(size_t)(r0 + ty + 8 * r) * C + c0 + tx];
    __syncthreads();
#pragma unroll
    for (int r = 0; r < 4; r++)
        dst[(size_t)(c0 + ty + 8 * r) * R + r0 + tx] = t[tx][ty + 8 * r];
}

// ---------------------------------------------------------------------------
// Max-plus tile kernel, single 64-k stage, 128j x 128b tile, 8x8 frag/thread.
// A: [K][512] K-major activations; W: [K][JDIM] K-major weights.
// Stores raw partial (no relu) transposed: P[z][j][b].
// Fragment split low/high 64-halves so all LDS reads are 2-way-aliased (free).
template <int JDIM>
__global__ __launch_bounds__(256) void morpho3(const float* __restrict__ A,
                                               const float* __restrict__ W,
                                               float* __restrict__ P) {
    __shared__ float lA[64 * 128];   // [k][b]  32KB
    __shared__ float lW[64 * 128];   // [k][j]  32KB
    const int t  = threadIdx.x;
    const int tx = t & 15;           // b frag: b0 + tx*4 + {0..3} and +64
    const int ty = t >> 4;           // j frag: j0 + ty*4 + {0..3} and +64
    const int j0 = blockIdx.x * 128;
    const int b0 = blockIdx.y * 128;
    const int k0 = blockIdx.z * 64;

    // ---- stage A and W tiles: 2048 float4 each, 8/thread each ----
#pragma unroll
    for (int r = 0; r < 8; r++) {
        const int q  = t + 256 * r;       // 0..2047
        const int kk = q >> 5, c = q & 31;
        ((float4*)lA)[q] = *((const float4*)(A + (size_t)(k0 + kk) * 512 + b0) + c);
        ((float4*)lW)[q] = *((const float4*)(W + (size_t)(k0 + kk) * JDIM + j0) + c);
    }
    __syncthreads();

    float acc[8][8];
#pragma unroll
    for (int jj = 0; jj < 8; jj++)
#pragma unroll
        for (int ii = 0; ii < 8; ii++) acc[jj][ii] = -3.402823466e38f;

    const float4* lA4 = (const float4*)lA;
    const float4* lW4 = (const float4*)lW;

    // ---- inner max-plus: 2 k's per iter so fmax pairs fuse to v_max3 ----
#pragma unroll 2
    for (int kk = 0; kk < 64; kk += 2) {
        float a0[8], a1[8], w0[8], w1[8];
        *(float4*)(a0)     = lA4[kk * 32 + tx];
        *(float4*)(a0 + 4) = lA4[kk * 32 + 16 + tx];
        *(float4*)(w0)     = lW4[kk * 32 + ty];
        *(float4*)(w0 + 4) = lW4[kk * 32 + 16 + ty];
        *(float4*)(a1)     = lA4[kk * 32 + 32 + tx];
        *(float4*)(a1 + 4) = lA4[kk * 32 + 48 + tx];
        *(float4*)(w1)     = lW4[kk * 32 + 32 + ty];
        *(float4*)(w1 + 4) = lW4[kk * 32 + 48 + ty];
#pragma unroll
        for (int jj = 0; jj < 8; jj++)
#pragma unroll
            for (int ii = 0; ii < 8; ii++)
                acc[jj][ii] =
                    fmaxf(fmaxf(acc[jj][ii], a0[ii] + w0[jj]), a1[ii] + w1[jj]);
    }

    // ---- store transposed partial: P[z][j][b], float4 over b (coalesced) ----
    float* Pp = P + (size_t)blockIdx.z * JDIM * 512;
#pragma unroll
    for (int jj = 0; jj < 8; jj++) {
        const int j = j0 + (jj < 4 ? ty * 4 + jj : 64 + ty * 4 + (jj - 4));
        *(float4*)(Pp + (size_t)j * 512 + b0 + tx * 4) =
            make_float4(acc[jj][0], acc[jj][1], acc[jj][2], acc[jj][3]);
        *(float4*)(Pp + (size_t)j * 512 + b0 + 64 + tx * 4) =
            make_float4(acc[jj][4], acc[jj][5], acc[jj][6], acc[jj][7]);
    }
}

// ---------------------------------------------------------------------------
// combineH: A2[j][b] = relu(max_z hp[z][j][b]).  Already K-major for L2.
__global__ __launch_bounds__(256) void combineH(const float* __restrict__ hp,
                                                float* __restrict__ A2) {
    const int i = blockIdx.x * 256 + threadIdx.x;   // float4 index
    const float4* p = (const float4*)hp;
    float4 m = p[i];
#pragma unroll
    for (int z = 1; z < 8; z++) {
        const float4 v = p[i + z * 131072];         // 512K floats / 4
        m.x = fmaxf(m.x, v.x);
        m.y = fmaxf(m.y, v.y);
        m.z = fmaxf(m.z, v.z);
        m.w = fmaxf(m.w, v.w);
    }
    m.x = fmaxf(m.x, 0.0f);
    m.y = fmaxf(m.y, 0.0f);
    m.z = fmaxf(m.z, 0.0f);
    m.w = fmaxf(m.w, 0.0f);
    ((float4*)A2)[i] = m;
}

// ---------------------------------------------------------------------------
// combineY: out[b][o] = relu(max_z yp[z][o][b]); 16 partials + transpose.
__global__ __launch_bounds__(256) void combineY(const float* __restrict__ yp,
                                                float* __restrict__ out) {
    __shared__ float t[32][33];
    const int id = blockIdx.x;
    const int ot = id & 15, bt = id >> 4;
    const int tx = threadIdx.x & 31, ty = threadIdx.x >> 5;
    const int o0 = ot * 32, b0 = bt * 32;
#pragma unroll
    for (int r = 0; r < 4; r++) {
        const int o   = o0 + ty + 8 * r;
        const int idx = o * 512 + b0 + tx;
        float m = yp[idx];
#pragma unroll
        for (int z = 1; z < 16; z++) m = fmaxf(m, yp[idx + z * 262144]);
        t[ty + 8 * r][tx] = fmaxf(m, 0.0f);
    }
    __syncthreads();
#pragma unroll
    for (int r = 0; r < 4; r++)
        out[(b0 + ty + 8 * r) * 512 + o0 + tx] = t[tx][ty + 8 * r];
}

// ---------------------------------------------------------------------------
extern "C" void kernel_launch(void* const* d_in, const int* in_sizes, int n_in,
                              void* d_out, int out_size, void* d_ws, size_t ws_size,
                              hipStream_t stream) {
    (void)in_sizes; (void)n_in; (void)out_size; (void)ws_size;
    const float* x  = (const float*)d_in[0];
    const float* W1 = (const float*)d_in[1];
    const float* W2 = (const float*)d_in[2];
    float* ws  = (float*)d_ws;
    float* out = (float*)d_out;

    // 1) K-major transposes of x, W1, W2
    transpose3<<<1280, 256, 0, stream>>>(x, W1, W2, ws);

    // 2) L1: hp[8][1024][512]; grid 8(j) x 4(b) x 8(kz) = 256 blocks
    morpho3<1024><<<dim3(8, 4, 8), 256, 0, stream>>>(
        ws + WS_XT, ws + WS_W1T, ws + WS_HP);

    // 3) combine 8 partials + relu -> A2[k2][b]
    combineH<<<512, 256, 0, stream>>>(ws + WS_HP, ws + WS_A2);

    // 4) L2: yp[16][512][512]; grid 4(j) x 4(b) x 16(kz) = 256 blocks
    morpho3<512><<<dim3(4, 4, 16), 256, 0, stream>>>(
        ws + WS_A2, ws + WS_W2T, ws + WS_YP);

    // 5) combine 16 partials + relu + transpose -> d_out[b][o]
    combineY<<<256, 256, 0, stream>>>(ws + WS_YP, out);
}

// Round 4
// 106.032 us; speedup vs baseline: 1.0453x; 1.0453x over previous
//
#include <hip/hip_runtime.h>

// MorphoMLP: y = relu(maxplus(relu(maxplus(x,W1)), W2)), fp32.
// B=512, IN=512, HID=1024, OUT=512.
// R4: balanced inner loop (frag 8x8 -> 1.0 B/pos LDS vs 85 B/cyc ceiling)
//     AND >=2 blocks/CU (Kchunk=32, LDS 32KB, grid 512).
//   transpose3 -> morpho4<1024> (z=16) -> combineH (max16+relu)
//   -> morpho4<512> (z=32) -> combineY (max32+relu+transpose)
// ws: xT 1MB | W1T 2MB | W2T 2MB | hp 32MB | A2 2MB | yp 32MB = 71MB

#define WS_XT   0                           // [512][512]     x^T  [k][b]
#define WS_W1T  (512 * 512)                 // [512][1024]    W1^T [k][j]
#define WS_W2T  (WS_W1T + 512 * 1024)       // [1024][512]    W2^T [k2][o]
#define WS_HP   (WS_W2T + 1024 * 512)       // [16][1024][512]  L1 partials
#define WS_A2   (WS_HP + 16 * 1024 * 512)   // [1024][512]    relu(h)^T [k2][b]
#define WS_YP   (WS_A2 + 1024 * 512)        // [32][512][512]   L2 partials

// ---------------------------------------------------------------------------
// Fused transpose of x (512x512), W1 (1024x512), W2 (512x1024) into ws.
__global__ __launch_bounds__(256) void transpose3(const float* __restrict__ x,
                                                  const float* __restrict__ W1,
                                                  const float* __restrict__ W2,
                                                  float* __restrict__ ws) {
    __shared__ float t[32][33];
    const int id = blockIdx.x;
    const float* src;
    float* dst;
    int R, C, rt, ct;
    if (id < 256) {
        src = x;  dst = ws + WS_XT;  R = 512;  C = 512;
        rt = id >> 4;          ct = id & 15;
    } else if (id < 768) {
        int b = id - 256;
        src = W1; dst = ws + WS_W1T; R = 1024; C = 512;
        rt = b >> 4;           ct = b & 15;
    } else {
        int b = id - 768;
        src = W2; dst = ws + WS_W2T; R = 512;  C = 1024;
        rt = b >> 5;           ct = b & 31;
    }
    const int tx = threadIdx.x & 31, ty = threadIdx.x >> 5;
    const int r0 = rt * 32, c0 = ct * 32;
#pragma unroll
    for (int r = 0; r < 4; r++)
        t[ty + 8 * r][tx] = src[(size_t)(r0 + ty + 8 * r) * C + c0 + tx];
    __syncthreads();
#pragma unroll
    for (int r = 0; r < 4; r++)
        dst[(size_t)(c0 + ty + 8 * r) * R + r0 + tx] = t[tx][ty + 8 * r];
}

// ---------------------------------------------------------------------------
// Max-plus tile kernel: 128j x 128b tile, 32-k single stage, 8x8 frag/thread.
// A: [K][512] K-major activations; W: [K][JDIM] K-major weights.
// Stores raw partial (no relu) transposed: P[z][j][b].
// LDS 32KB -> with launch_bounds(256,2) two blocks/CU guaranteed resident.
template <int JDIM>
__global__ __launch_bounds__(256, 2) void morpho4(const float* __restrict__ A,
                                                  const float* __restrict__ W,
                                                  float* __restrict__ P) {
    __shared__ float lA[32 * 128];   // [k][b]  16KB
    __shared__ float lW[32 * 128];   // [k][j]  16KB
    const int t  = threadIdx.x;
    const int tx = t & 15;           // b frag: b0 + tx*4 + {0..3} and +64
    const int ty = t >> 4;           // j frag: j0 + ty*4 + {0..3} and +64
    const int j0 = blockIdx.x * 128;
    const int b0 = blockIdx.y * 128;
    const int k0 = blockIdx.z * 32;

    // ---- stage A and W tiles: 1024 float4 each, 4/thread each ----
#pragma unroll
    for (int r = 0; r < 4; r++) {
        const int q  = t + 256 * r;       // 0..1023
        const int kk = q >> 5, c = q & 31;
        ((float4*)lA)[q] = *((const float4*)(A + (size_t)(k0 + kk) * 512 + b0) + c);
        ((float4*)lW)[q] = *((const float4*)(W + (size_t)(k0 + kk) * JDIM + j0) + c);
    }
    __syncthreads();

    float acc[8][8];
#pragma unroll
    for (int jj = 0; jj < 8; jj++)
#pragma unroll
        for (int ii = 0; ii < 8; ii++) acc[jj][ii] = -3.402823466e38f;

    const float4* lA4 = (const float4*)lA;
    const float4* lW4 = (const float4*)lW;

    // ---- inner max-plus: 2 k's per iter so fmax pairs fuse to v_max3 ----
#pragma unroll 2
    for (int kk = 0; kk < 32; kk += 2) {
        float a0[8], a1[8], w0[8], w1[8];
        *(float4*)(a0)     = lA4[kk * 32 + tx];
        *(float4*)(a0 + 4) = lA4[kk * 32 + 16 + tx];
        *(float4*)(w0)     = lW4[kk * 32 + ty];
        *(float4*)(w0 + 4) = lW4[kk * 32 + 16 + ty];
        *(float4*)(a1)     = lA4[kk * 32 + 32 + tx];
        *(float4*)(a1 + 4) = lA4[kk * 32 + 48 + tx];
        *(float4*)(w1)     = lW4[kk * 32 + 32 + ty];
        *(float4*)(w1 + 4) = lW4[kk * 32 + 48 + ty];
#pragma unroll
        for (int jj = 0; jj < 8; jj++)
#pragma unroll
            for (int ii = 0; ii < 8; ii++)
                acc[jj][ii] =
                    fmaxf(fmaxf(acc[jj][ii], a0[ii] + w0[jj]), a1[ii] + w1[jj]);
    }

    // ---- store transposed partial: P[z][j][b], float4 over b (coalesced) ----
    float* Pp = P + (size_t)blockIdx.z * JDIM * 512;
#pragma unroll
    for (int jj = 0; jj < 8; jj++) {
        const int j = j0 + (jj < 4 ? ty * 4 + jj : 64 + ty * 4 + (jj - 4));
        *(float4*)(Pp + (size_t)j * 512 + b0 + tx * 4) =
            make_float4(acc[jj][0], acc[jj][1], acc[jj][2], acc[jj][3]);
        *(float4*)(Pp + (size_t)j * 512 + b0 + 64 + tx * 4) =
            make_float4(acc[jj][4], acc[jj][5], acc[jj][6], acc[jj][7]);
    }
}

// ---------------------------------------------------------------------------
// combineH: A2[j][b] = relu(max_z hp[z][j][b]), z<16.  K-major for L2.
__global__ __launch_bounds__(256) void combineH(const float* __restrict__ hp,
                                                float* __restrict__ A2) {
    const int i = blockIdx.x * 256 + threadIdx.x;   // float4 index, 131072 total
    const float4* p = (const float4*)hp;
    float4 m = p[i];
#pragma unroll
    for (int z = 1; z < 16; z++) {
        const float4 v = p[i + z * 131072];         // 512K floats / 4 per z
        m.x = fmaxf(m.x, v.x);
        m.y = fmaxf(m.y, v.y);
        m.z = fmaxf(m.z, v.z);
        m.w = fmaxf(m.w, v.w);
    }
    m.x = fmaxf(m.x, 0.0f);
    m.y = fmaxf(m.y, 0.0f);
    m.z = fmaxf(m.z, 0.0f);
    m.w = fmaxf(m.w, 0.0f);
    ((float4*)A2)[i] = m;
}

// ---------------------------------------------------------------------------
// combineY: out[b][o] = relu(max_z yp[z][o][b]), z<32; + transpose.
__global__ __launch_bounds__(256) void combineY(const float* __restrict__ yp,
                                                float* __restrict__ out) {
    __shared__ float t[32][33];
    const int id = blockIdx.x;
    const int ot = id & 15, bt = id >> 4;
    const int tx = threadIdx.x & 31, ty = threadIdx.x >> 5;
    const int o0 = ot * 32, b0 = bt * 32;
#pragma unroll
    for (int r = 0; r < 4; r++) {
        const int o   = o0 + ty + 8 * r;
        const int idx = o * 512 + b0 + tx;
        float m = yp[idx];
#pragma unroll
        for (int z = 1; z < 32; z++) m = fmaxf(m, yp[idx + z * 262144]);
        t[ty + 8 * r][tx] = fmaxf(m, 0.0f);
    }
    __syncthreads();
#pragma unroll
    for (int r = 0; r < 4; r++)
        out[(b0 + ty + 8 * r) * 512 + o0 + tx] = t[tx][ty + 8 * r];
}

// ---------------------------------------------------------------------------
extern "C" void kernel_launch(void* const* d_in, const int* in_sizes, int n_in,
                              void* d_out, int out_size, void* d_ws, size_t ws_size,
                              hipStream_t stream) {
    (void)in_sizes; (void)n_in; (void)out_size; (void)ws_size;
    const float* x  = (const float*)d_in[0];
    const float* W1 = (const float*)d_in[1];
    const float* W2 = (const float*)d_in[2];
    float* ws  = (float*)d_ws;
    float* out = (float*)d_out;

    // 1) K-major transposes of x, W1, W2
    transpose3<<<1280, 256, 0, stream>>>(x, W1, W2, ws);

    // 2) L1: hp[16][1024][512]; grid 8(j) x 4(b) x 16(kz) = 512 blocks (2/CU)
    morpho4<1024><<<dim3(8, 4, 16), 256, 0, stream>>>(
        ws + WS_XT, ws + WS_W1T, ws + WS_HP);

    // 3) combine 16 partials + relu -> A2[k2][b]
    combineH<<<512, 256, 0, stream>>>(ws + WS_HP, ws + WS_A2);

    // 4) L2: yp[32][512][512]; grid 4(j) x 4(b) x 32(kz) = 512 blocks (2/CU)
    morpho4<512><<<dim3(4, 4, 32), 256, 0, stream>>>(
        ws + WS_A2, ws + WS_W2T, ws + WS_YP);

    // 5) combine 32 partials + relu + transpose -> d_out[b][o]
    combineY<<<256, 256, 0, stream>>>(ws + WS_YP, out);
}